// Round 16
// baseline (903.660 us; speedup 1.0000x reference)
//
#include <hip/hip_runtime.h>

#define NITEMS 169

typedef __attribute__((ext_vector_type(8))) __bf16 bf16x8;
typedef __attribute__((ext_vector_type(4))) float f32x4;
typedef __attribute__((ext_vector_type(8))) unsigned short u16x8;
typedef __attribute__((ext_vector_type(4))) unsigned short u16x4;

__device__ __forceinline__ unsigned short f2b(float x) {
  union { float f; unsigned u; } v; v.f = x;
  unsigned r = v.u + 0x7fffu + ((v.u >> 16) & 1u);
  return (unsigned short)(r >> 16);
}
// HW RNE float->bf16 (identical result for finite values)
__device__ __forceinline__ unsigned short f2b2(float x) {
  __bf16 b = (__bf16)x;
  union { __bf16 b; unsigned short u; } v; v.b = b;
  return v.u;
}
__device__ __forceinline__ float b2f(unsigned short u) {
  union { unsigned u; float f; } v; v.u = ((unsigned)u) << 16;
  return v.f;
}

// f32 NCHW (32,64,128) -> bf16 NHWC (64,128,32)
__global__ __launch_bounds__(256) void k_prepf(const float* __restrict__ f,
                                               unsigned short* __restrict__ fb) {
  const int pix = blockIdx.x * 256 + threadIdx.x;
  const int y = pix >> 7, x = pix & 127;
#pragma unroll
  for (int c = 0; c < 32; ++c)
    fb[(size_t)pix * 32 + c] = f2b(f[(c * 64 + y) * 128 + x]);
}

// Pack 3x3 conv weights [Cout][Cin][3][3] f32 -> [cic][tap][cout][32ci] bf16
__global__ void k_prep3x3(const float* __restrict__ w, unsigned short* __restrict__ wp,
                          int Cout, int Cin) {
  int i = blockIdx.x * 256 + threadIdx.x;
  if (i >= Cout * Cin * 9) return;
  int kx = i % 3, t = i / 3;
  int ky = t % 3; t /= 3;
  int cin = t % Cin, cout = t / Cin;
  int tap = ky * 3 + kx;
  wp[(((cin >> 5) * 9 + tap) * Cout + cout) * 32 + (cin & 31)] = f2b(w[i]);
}

// Pack deconv weights [32][64][4][4] f32 -> [cic][ky][kx][cout][32ci] bf16
__global__ void k_prepwd(const float* __restrict__ w, unsigned short* __restrict__ wp) {
  int i = blockIdx.x * 256 + threadIdx.x;
  if (i >= 32 * 64 * 16) return;
  int kx = i & 3, ky = (i >> 2) & 3, ci = (i >> 4) & 63, cout = i >> 10;
  wp[(((((ci >> 5) * 4 + ky) * 4 + kx) * 32) + cout) * 32 + (ci & 31)] = f2b(w[i]);
}

// ---------------------------------------------------------------------------
// Z1 = conv3x3(f1, w1[:, 0:32]) on (64,128), no relu. NHWC bf16 out
// (1.5 MB -> L2-resident everywhere).
// ---------------------------------------------------------------------------
__global__ __launch_bounds__(256) void k_z1(
    const unsigned short* __restrict__ f1b, const unsigned short* __restrict__ wp,
    unsigned short* __restrict__ z1) {
  const int oy0 = blockIdx.x * 2;
  constexpr int WI = 130;
  __shared__ __align__(16) unsigned short X[4][4][WI][8];
  const int wid = threadIdx.x >> 6, lane = threadIdx.x & 63;
  const int lm = lane & 15, lkg = lane >> 4, lk = lkg * 8;

  f32x4 acc[24];
#pragma unroll
  for (int t = 0; t < 24; ++t) acc[t] = f32x4{0.f, 0.f, 0.f, 0.f};

  for (int c = threadIdx.x; c < 4 * 4 * WI; c += 256) {
    const int cig = c & 3, t2 = c >> 2;
    const int col = t2 % WI, r = t2 / WI;
    const int iy = oy0 - 1 + r, ix = col - 1;
    u16x8 v = {0, 0, 0, 0, 0, 0, 0, 0};
    if ((unsigned)iy < 64u && (unsigned)ix < 128u)
      v = *(const u16x8*)&f1b[(size_t)(iy * 128 + ix) * 32 + cig * 8];
    *(u16x8*)&X[r][cig][col][0] = v;
  }
  __syncthreads();
#pragma unroll
  for (int tap = 0; tap < 9; ++tap) {
    const int ky = tap / 3, kx = tap % 3;
    bf16x8 bf[4];
#pragma unroll
    for (int j = 0; j < 4; ++j) {
      const int mt = wid * 4 + j, rw = mt >> 3, mtx = mt & 7;
      bf[j] = *(const bf16x8*)&X[rw + ky][lkg][mtx * 16 + lm + kx][0];
    }
#pragma unroll
    for (int i = 0; i < 6; ++i) {
      bf16x8 af = *(const bf16x8*)&wp[((0 * 9 + tap) * 96 + i * 16 + lm) * 32 + lk];
#pragma unroll
      for (int j = 0; j < 4; ++j)
        acc[i * 4 + j] =
            __builtin_amdgcn_mfma_f32_16x16x32_bf16(af, bf[j], acc[i * 4 + j], 0, 0, 0);
    }
  }
#pragma unroll
  for (int i = 0; i < 6; ++i)
#pragma unroll
    for (int j = 0; j < 4; ++j) {
      const int mt = wid * 4 + j, rw = mt >> 3, mtx = mt & 7;
      const int cout0 = i * 16 + lkg * 4;
      const int m = mtx * 16 + lm;
      u16x4 pv;
#pragma unroll
      for (int r = 0; r < 4; ++r) pv[r] = f2b(acc[i * 4 + j][r]);
      *(u16x4*)&z1[(size_t)((oy0 + rw) * 128 + m) * 96 + cout0] = pv;
    }
}

// ---------------------------------------------------------------------------
// Z2ext = conv3x3(zero-padded f2, w1[:, 32:64]) on (76,140). NHWC bf16
// (2.0 MB -> L2-resident).
// ---------------------------------------------------------------------------
__global__ __launch_bounds__(256) void k_z2e(
    const unsigned short* __restrict__ f2b_, const unsigned short* __restrict__ wp,
    unsigned short* __restrict__ z2e) {
  const int u = blockIdx.x;  // 0..75
  constexpr int WI = 194;
  __shared__ __align__(16) unsigned short X[3][4][WI][8];
  const int wid = threadIdx.x >> 6, lane = threadIdx.x & 63;
  const int lm = lane & 15, lkg = lane >> 4, lk = lkg * 8;

  f32x4 acc[18];
#pragma unroll
  for (int t = 0; t < 18; ++t) acc[t] = f32x4{0.f, 0.f, 0.f, 0.f};

  for (int c = threadIdx.x; c < 3 * 4 * WI; c += 256) {
    const int cig = c & 3, t2 = c >> 2;
    const int col = t2 % WI, r = t2 / WI;
    const int iy = u + r - 7, ix = col - 7;
    u16x8 v = {0, 0, 0, 0, 0, 0, 0, 0};
    if ((unsigned)iy < 64u && (unsigned)ix < 128u)
      v = *(const u16x8*)&f2b_[(size_t)(iy * 128 + ix) * 32 + cig * 8];
    *(u16x8*)&X[r][cig][col][0] = v;
  }
  __syncthreads();
#pragma unroll
  for (int tap = 0; tap < 9; ++tap) {
    const int ky = tap / 3, kx = tap % 3;
    bf16x8 bf[3];
#pragma unroll
    for (int j = 0; j < 3; ++j) {
      const int mt = wid * 3 + j;
      bf[j] = *(const bf16x8*)&X[ky][lkg][mt * 16 + lm + kx][0];
    }
#pragma unroll
    for (int i = 0; i < 6; ++i) {
      bf16x8 af = *(const bf16x8*)&wp[((1 * 9 + tap) * 96 + i * 16 + lm) * 32 + lk];
#pragma unroll
      for (int j = 0; j < 3; ++j)
        acc[i * 3 + j] =
            __builtin_amdgcn_mfma_f32_16x16x32_bf16(af, bf[j], acc[i * 3 + j], 0, 0, 0);
    }
  }
#pragma unroll
  for (int i = 0; i < 6; ++i)
#pragma unroll
    for (int j = 0; j < 3; ++j) {
      const int v = (wid * 3 + j) * 16 + lm;
      if (v < 140) {
        const int cout0 = i * 16 + lkg * 4;
        u16x4 pv;
#pragma unroll
        for (int r = 0; r < 4; ++r) pv[r] = f2b(acc[i * 3 + j][r]);
        *(u16x4*)&z2e[(size_t)(u * 140 + v) * 96 + cout0] = pv;
      }
    }
}

// ---------------------------------------------------------------------------
// Crow[dyi] = conv3x3(f1 * row-band(dy), w1a); fp32 out [13][8][128][96].
// ---------------------------------------------------------------------------
__global__ __launch_bounds__(256) void k_crow(
    const unsigned short* __restrict__ f1b, const unsigned short* __restrict__ wp,
    float* __restrict__ crow) {
  const int dyi = blockIdx.x / 7, r = blockIdx.x % 7;
  const int dy = dyi - 6;
  const int ady = dy < 0 ? -dy : dy;
  if (dy == 0 || r >= ady + 1) return;
  const int rowlo = dy > 0 ? 63 - dy : 0;
  const int oy = rowlo + r;
  constexpr int WI = 130;
  __shared__ __align__(16) unsigned short X[3][4][WI][8];
  const int wid = threadIdx.x >> 6, lane = threadIdx.x & 63;
  const int lm = lane & 15, lkg = lane >> 4, lk = lkg * 8;

  f32x4 acc[12];
#pragma unroll
  for (int t = 0; t < 12; ++t) acc[t] = f32x4{0.f, 0.f, 0.f, 0.f};

  for (int c = threadIdx.x; c < 3 * 4 * WI; c += 256) {
    const int cig = c & 3, t2 = c >> 2;
    const int col = t2 % WI, rr = t2 / WI;
    const int iy = oy - 1 + rr, ix = col - 1;
    const bool band = dy > 0 ? (iy >= 64 - dy) : (iy < -dy);
    u16x8 v = {0, 0, 0, 0, 0, 0, 0, 0};
    if (band && (unsigned)iy < 64u && (unsigned)ix < 128u)
      v = *(const u16x8*)&f1b[(size_t)(iy * 128 + ix) * 32 + cig * 8];
    *(u16x8*)&X[rr][cig][col][0] = v;
  }
  __syncthreads();
#pragma unroll
  for (int tap = 0; tap < 9; ++tap) {
    const int ky = tap / 3, kx = tap % 3;
    bf16x8 bf[2];
#pragma unroll
    for (int j = 0; j < 2; ++j)
      bf[j] = *(const bf16x8*)&X[ky][lkg][(wid * 2 + j) * 16 + lm + kx][0];
#pragma unroll
    for (int i = 0; i < 6; ++i) {
      bf16x8 af = *(const bf16x8*)&wp[((0 * 9 + tap) * 96 + i * 16 + lm) * 32 + lk];
#pragma unroll
      for (int j = 0; j < 2; ++j)
        acc[i * 2 + j] =
            __builtin_amdgcn_mfma_f32_16x16x32_bf16(af, bf[j], acc[i * 2 + j], 0, 0, 0);
    }
  }
#pragma unroll
  for (int i = 0; i < 6; ++i)
#pragma unroll
    for (int j = 0; j < 2; ++j) {
      const int cout0 = i * 16 + lkg * 4;
      const int m = (wid * 2 + j) * 16 + lm;
      *(f32x4*)&crow[(size_t)((dyi * 8 + r) * 128 + m) * 96 + cout0] = acc[i * 2 + j];
    }
}

// ---------------------------------------------------------------------------
// Ccol[dxi] = conv3x3(f1 * col-band(dx), w1a); fp32 out [13][64][8][96].
// ---------------------------------------------------------------------------
__global__ __launch_bounds__(256) void k_ccol(
    const unsigned short* __restrict__ f1b, const unsigned short* __restrict__ wp,
    float* __restrict__ ccol) {
  const int dxi = blockIdx.x;
  const int dx = dxi - 6;
  const int adx = dx < 0 ? -dx : dx;
  if (dx == 0) return;
  const int ccnt = adx + 1;
  const int collo = dx > 0 ? 127 - dx : 0;
  __shared__ __align__(16) unsigned short X2[9][66][32];
  const int wid = threadIdx.x >> 6, lane = threadIdx.x & 63;
  const int lm = lane & 15, lkg = lane >> 4, lk = lkg * 8;

  for (int t = threadIdx.x; t < 9 * 66 * 4; t += 256) {
    const int cig = t & 3, pos = t >> 2;
    const int rr = pos % 66, cc = pos / 66;
    const int iy = rr - 1, ix = collo - 1 + cc;
    const bool band = dx > 0 ? (ix >= 128 - dx) : (ix < -dx);
    u16x8 v = {0, 0, 0, 0, 0, 0, 0, 0};
    if (band && (unsigned)iy < 64u && (unsigned)ix < 128u)
      v = *(const u16x8*)&f1b[(size_t)(iy * 128 + ix) * 32 + cig * 8];
    *(u16x8*)&X2[cc][rr][cig * 8] = v;
  }
  __syncthreads();
  for (int c = 0; c < ccnt; ++c) {
    f32x4 acc[6];
#pragma unroll
    for (int i = 0; i < 6; ++i) acc[i] = f32x4{0.f, 0.f, 0.f, 0.f};
#pragma unroll
    for (int tap = 0; tap < 9; ++tap) {
      const int ky = tap / 3, kx = tap % 3;
      bf16x8 bf = *(const bf16x8*)&X2[c + kx][wid * 16 + lm + ky][lk];
#pragma unroll
      for (int i = 0; i < 6; ++i) {
        bf16x8 af = *(const bf16x8*)&wp[((0 * 9 + tap) * 96 + i * 16 + lm) * 32 + lk];
        acc[i] = __builtin_amdgcn_mfma_f32_16x16x32_bf16(af, bf, acc[i], 0, 0, 0);
      }
    }
    const int y = wid * 16 + lm;
#pragma unroll
    for (int i = 0; i < 6; ++i) {
      const int cout0 = i * 16 + lkg * 4;
      *(f32x4*)&ccol[(size_t)((dxi * 64 + y) * 8 + c) * 96 + cout0] = acc[i];
    }
  }
}

// ---------------------------------------------------------------------------
// Vectorized bf16 dot over 32 channels.
// ---------------------------------------------------------------------------
__device__ __forceinline__ float dot32(const unsigned short* __restrict__ xv,
                                       const unsigned short* __restrict__ wv) {
  float s = 0.f;
#pragma unroll
  for (int cg = 0; cg < 4; ++cg) {
    u16x8 a = *(const u16x8*)&xv[cg * 8];
    u16x8 b = *(const u16x8*)&wv[cg * 8];
#pragma unroll
    for (int e = 0; e < 8; ++e) s += b2f(a[e]) * b2f(b[e]);
  }
  return s;
}

// ---------------------------------------------------------------------------
// Ccorner: one thread per (item, r, c, co). 169*8*8*96 outputs.
// ---------------------------------------------------------------------------
__global__ __launch_bounds__(256) void k_ccorner(
    const unsigned short* __restrict__ f1b, const unsigned short* __restrict__ w1p,
    float* __restrict__ ccor) {
  const int idx = blockIdx.x * 256 + threadIdx.x;
  if (idx >= NITEMS * 64 * 96) return;
  const int co = idx % 96, t = idx / 96;
  const int c = t & 7, r = (t >> 3) & 7, item = t >> 6;
  const int dx = item / 13 - 6, dy = item % 13 - 6;
  if (dx == 0 || dy == 0) return;
  const int ady = dy < 0 ? -dy : dy, adx = dx < 0 ? -dx : dx;
  if (r >= ady + 1 || c >= adx + 1) return;
  const int rowlo = dy > 0 ? 63 - dy : 0;
  const int collo = dx > 0 ? 127 - dx : 0;
  const int oy = rowlo + r, ox = collo + c;
  float acc = 0.f;
#pragma unroll
  for (int ky = 0; ky < 3; ++ky)
#pragma unroll
    for (int kx = 0; kx < 3; ++kx) {
      const int iy = oy - 1 + ky, ix = ox - 1 + kx;
      const bool rb = dy > 0 ? (iy >= 64 - dy) : (iy < -dy);
      const bool cb = dx > 0 ? (ix >= 128 - dx) : (ix < -dx);
      if (rb && cb && (unsigned)iy < 64u && (unsigned)ix < 128u)
        acc += dot32(&f1b[(size_t)(iy * 128 + ix) * 32],
                     &w1p[((ky * 3 + kx) * 96 + co) * 32]);
    }
  ccor[(size_t)(((item * 8 + r) * 8 + c) * 96) + co] = acc;
}

// rtop/rbot[dyi][v][co]: one thread per (dyi,v,co). 13*140*96 outputs.
__global__ __launch_bounds__(256) void k_bcorr_rows(
    const unsigned short* __restrict__ f2bp, const unsigned short* __restrict__ w1p,
    float* __restrict__ rtop, float* __restrict__ rbot) {
  const int idx = blockIdx.x * 256 + threadIdx.x;
  if (idx >= 13 * 140 * 96) return;
  const int co = idx % 96, t = idx / 96;
  const int v = t % 140, dyi = t / 140;
  const int dy = dyi - 6;
  const int rt = dy - 1, rb = 64 + dy;
  float at = 0.f, ab = 0.f;
#pragma unroll
  for (int kx = 0; kx < 3; ++kx) {
    const int x2 = v - 7 + kx;
    if ((unsigned)x2 >= 128u) continue;
    if ((unsigned)rt < 64u)
      at += dot32(&f2bp[(size_t)(rt * 128 + x2) * 32],
                  &w1p[((9 + 0 + kx) * 96 + co) * 32]);
    if ((unsigned)rb < 64u)
      ab += dot32(&f2bp[(size_t)(rb * 128 + x2) * 32],
                  &w1p[((9 + 6 + kx) * 96 + co) * 32]);
  }
  rtop[idx] = at;
  rbot[idx] = ab;
}

// clft/crgt[dxi][u][co]: one thread per (dxi,u,co). 13*76*96 outputs.
__global__ __launch_bounds__(256) void k_bcorr_cols(
    const unsigned short* __restrict__ f2bp, const unsigned short* __restrict__ w1p,
    float* __restrict__ clft, float* __restrict__ crgt) {
  const int idx = blockIdx.x * 256 + threadIdx.x;
  if (idx >= 13 * 76 * 96) return;
  const int co = idx % 96, t = idx / 96;
  const int u = t % 76, dxi = t / 76;
  const int dx = dxi - 6;
  const int cl = dx - 1, cr = 128 + dx;
  float al = 0.f, ar = 0.f;
#pragma unroll
  for (int ky = 0; ky < 3; ++ky) {
    const int y2 = u - 7 + ky;
    if ((unsigned)y2 >= 64u) continue;
    if ((unsigned)cl < 128u)
      al += dot32(&f2bp[(size_t)(y2 * 128 + cl) * 32],
                  &w1p[((9 + ky * 3 + 0) * 96 + co) * 32]);
    if ((unsigned)cr < 128u)
      ar += dot32(&f2bp[(size_t)(y2 * 128 + cr) * 32],
                  &w1p[((9 + ky * 3 + 2) * 96 + co) * 32]);
  }
  clft[idx] = al;
  crgt[idx] = ar;
}

// kcorn[item][corner][co]: one thread per output. 169*4*96 outputs.
__global__ __launch_bounds__(256) void k_bcorr_corn(
    const unsigned short* __restrict__ f2bp, const unsigned short* __restrict__ w1p,
    float* __restrict__ kcorn) {
  const int idx = blockIdx.x * 256 + threadIdx.x;
  if (idx >= NITEMS * 4 * 96) return;
  const int co = idx % 96, t = idx / 96;
  const int corner = t % 4, item = t / 4;
  const int dx = item / 13 - 6, dy = item % 13 - 6;
  const int row = (corner < 2) ? dy - 1 : 64 + dy;
  const int col = (corner & 1) ? 128 + dx : dx - 1;
  const int ky = (corner < 2) ? 0 : 2;
  const int kx = (corner & 1) ? 2 : 0;
  float acc = 0.f;
  if ((unsigned)row < 64u && (unsigned)col < 128u)
    acc = dot32(&f2bp[(size_t)(row * 128 + col) * 32],
                &w1p[((9 + ky * 3 + kx) * 96 + co) * 32]);
  kcorn[idx] = acc;
}

// ---------------------------------------------------------------------------
// Full correction formula (8 channels at c0), bf16 z1/z2e terms.
// Only for correction pixels.
// ---------------------------------------------------------------------------
struct ItemGeo {
  int item, dx, dy, dyi, dxi, rowlo, rowhi, collo, colhi;
};

__device__ __forceinline__ u16x8 x1_fuse8(
    const unsigned short* __restrict__ z1b, const unsigned short* __restrict__ z2eb,
    const float* __restrict__ crow, const float* __restrict__ ccol,
    const float* __restrict__ ccor, const float* __restrict__ rtop,
    const float* __restrict__ rbot, const float* __restrict__ clft,
    const float* __restrict__ crgt, const float* __restrict__ kcorn,
    const ItemGeo& gm, int y, int px, int c0) {
  const bool inrow = (y >= gm.rowlo) && (y < gm.rowhi);
  const bool incol = (px >= gm.collo) && (px < gm.colhi);
  const int vrow = y + gm.dy + 6;
  const int v = px + gm.dx + 6;
  u16x8 a = *(const u16x8*)&z1b[(size_t)(y * 128 + px) * 96 + c0];
  u16x8 b = *(const u16x8*)&z2eb[(size_t)(vrow * 140 + v) * 96 + c0];
  u16x8 o;
#pragma unroll
  for (int h = 0; h < 2; ++h) {
    const int cc = c0 + h * 4;
    f32x4 s;
#pragma unroll
    for (int e = 0; e < 4; ++e) s[e] = b2f(a[h * 4 + e]) + b2f(b[h * 4 + e]);
    if (inrow)
      s -= *(const f32x4*)&crow[(size_t)((gm.dyi * 8 + y - gm.rowlo) * 128 + px) * 96 + cc];
    if (incol) {
      s -= *(const f32x4*)&ccol[(size_t)((gm.dxi * 64 + y) * 8 + px - gm.collo) * 96 + cc];
      if (inrow)
        s += *(const f32x4*)&ccor[(size_t)(((gm.item * 8 + y - gm.rowlo) * 8) + px - gm.collo) * 96 + cc];
    }
    if (y == 0) s -= *(const f32x4*)&rtop[(size_t)(gm.dyi * 140 + v) * 96 + cc];
    if (y == 63) s -= *(const f32x4*)&rbot[(size_t)(gm.dyi * 140 + v) * 96 + cc];
    if (px == 0) s -= *(const f32x4*)&clft[(size_t)(gm.dxi * 76 + vrow) * 96 + cc];
    if (px == 127) s -= *(const f32x4*)&crgt[(size_t)(gm.dxi * 76 + vrow) * 96 + cc];
    if (y == 0 && px == 0) s += *(const f32x4*)&kcorn[(size_t)gm.item * 384 + 0 * 96 + cc];
    if (y == 0 && px == 127) s += *(const f32x4*)&kcorn[(size_t)gm.item * 384 + 1 * 96 + cc];
    if (y == 63 && px == 0) s += *(const f32x4*)&kcorn[(size_t)gm.item * 384 + 2 * 96 + cc];
    if (y == 63 && px == 127) s += *(const f32x4*)&kcorn[(size_t)gm.item * 384 + 3 * 96 + cc];
#pragma unroll
    for (int e = 0; e < 4; ++e) o[h * 4 + e] = f2b(fmaxf(s[e], 0.f));
  }
  return o;
}

// ---------------------------------------------------------------------------
// Fused assemble+conv2 (R15 structure) with strength-reduced staging
// addressing: no div/mod, block-uniform row offsets/predicates hoisted,
// shared col*96 term for both buffers. Math unchanged.
// Out x2 NHWC bf16 (32,64,128).
// ---------------------------------------------------------------------------
__global__ __launch_bounds__(256) void k_conv2f(
    const unsigned short* __restrict__ z1b, const unsigned short* __restrict__ z2eb,
    const float* __restrict__ crow, const float* __restrict__ ccol,
    const float* __restrict__ ccor, const float* __restrict__ rtop,
    const float* __restrict__ rbot, const float* __restrict__ clft,
    const float* __restrict__ crgt, const float* __restrict__ kcorn,
    const unsigned short* __restrict__ wp, unsigned short* __restrict__ x2,
    int base) {
  constexpr int WI = 130, WIH = 65;
  const int g = blockIdx.y, oy = blockIdx.x;
  const int item = base + g;
  ItemGeo gm;
  gm.item = item;
  gm.dx = item / 13 - 6;
  gm.dy = item % 13 - 6;
  gm.dyi = gm.dy + 6;
  gm.dxi = gm.dx + 6;
  {
    const int ady = gm.dy < 0 ? -gm.dy : gm.dy, adx = gm.dx < 0 ? -gm.dx : gm.dx;
    gm.rowlo = gm.dy > 0 ? 63 - gm.dy : 0;
    gm.rowhi = gm.rowlo + (gm.dy ? ady + 1 : 0);
    gm.collo = gm.dx > 0 ? 127 - gm.dx : 0;
    gm.colhi = gm.collo + (gm.dx ? adx + 1 : 0);
  }
  unsigned short* op = x2 + (size_t)g * (128 * 2048);
  __shared__ __align__(16) unsigned short X[3][4][WI][8];
  const int wid = threadIdx.x >> 6, lane = threadIdx.x & 63;
  const int lm = lane & 15, lkg = lane >> 4, lk = lkg * 8;
  const int ct0 = wid * 2;

  // Block-uniform per-row staging constants (iy = oy*2-1+r).
  int rowoff1[3], rowoff2[3];
  bool rowokA[3], rowcA[3];
#pragma unroll
  for (int r = 0; r < 3; ++r) {
    const int iy = oy * 2 - 1 + r;
    rowokA[r] = (unsigned)iy < 64u;
    rowcA[r] = rowokA[r] &&
               ((iy >= gm.rowlo && iy < gm.rowhi) || iy == 0 || iy == 63);
    rowoff1[r] = iy * (128 * 96) - 96;                               // + col*96 + ch
    rowoff2[r] = (iy + gm.dy + 6) * (140 * 96) + (gm.dx + 5) * 96;   // + col*96 + ch
  }
  const int cig = threadIdx.x & 3;
  const int idx0 = threadIdx.x >> 2;  // 0..63, walks +64

  f32x4 acc[8];
#pragma unroll
  for (int t = 0; t < 8; ++t) acc[t] = f32x4{0.f, 0.f, 0.f, 0.f};

  for (int cic = 0; cic < 3; ++cic) {
    const int ch = cic * 32 + cig * 8;
    __syncthreads();
#pragma unroll
    for (int k = 0; k < 7; ++k) {
      const int idx = idx0 + 64 * k;      // 0..389 over (r,col)
      if (idx >= 390) break;
      const int r = (idx >= 260) ? 2 : (idx >= 130 ? 1 : 0);
      const int col = idx - r * 130;
      const int ix = col - 1;
      const int pcol = (col >> 1) + (col & 1) * WIH;
      u16x8 v = {0, 0, 0, 0, 0, 0, 0, 0};
      if (rowokA[r] && (unsigned)ix < 128u) {
        const bool colc = (ix >= gm.collo && ix < gm.colhi) || ix == 0 || ix == 127;
        if (rowcA[r] || colc) {
          const int iy = oy * 2 - 1 + r;
          v = x1_fuse8(z1b, z2eb, crow, ccol, ccor, rtop, rbot, clft, crgt, kcorn,
                       gm, iy, ix, ch);
        } else {
          const int c96 = col * 96;
          const unsigned short* p1 = z1b + rowoff1[r] + c96 + ch;
          const unsigned short* p2 = z2eb + rowoff2[r] + c96 + ch;
          u16x8 a = *(const u16x8*)p1;
          u16x8 b = *(const u16x8*)p2;
#pragma unroll
          for (int e = 0; e < 8; ++e)
            v[e] = f2b2(fmaxf(b2f(a[e]) + b2f(b[e]), 0.f));
        }
      }
      *(u16x8*)&X[r][cig][pcol][0] = v;
    }
    __syncthreads();
#pragma unroll
    for (int tap = 0; tap < 9; ++tap) {
      const int ky = tap / 3, kx = tap % 3;
      bf16x8 bf[4];
#pragma unroll
      for (int j = 0; j < 4; ++j) {
        const int m = j * 16 + lm;
        const int colr = m + (kx >> 1) + (kx & 1) * WIH;
        bf[j] = *(const bf16x8*)&X[ky][lkg][colr][0];
      }
#pragma unroll
      for (int i = 0; i < 2; ++i) {
        const int cout = (ct0 + i) * 16 + lm;
        bf16x8 af = *(const bf16x8*)&wp[((cic * 9 + tap) * 128 + cout) * 32 + lk];
#pragma unroll
        for (int j = 0; j < 4; ++j)
          acc[i * 4 + j] =
              __builtin_amdgcn_mfma_f32_16x16x32_bf16(af, bf[j], acc[i * 4 + j], 0, 0, 0);
      }
    }
  }
#pragma unroll
  for (int i = 0; i < 2; ++i)
#pragma unroll
    for (int j = 0; j < 4; ++j) {
      const int cout0 = (ct0 + i) * 16 + lkg * 4;
      const int m = j * 16 + lm;
      u16x4 pv;
#pragma unroll
      for (int r = 0; r < 4; ++r) pv[r] = f2b(fmaxf(acc[i * 4 + j][r], 0.f));
      *(u16x4*)&op[(size_t)(oy * 64 + m) * 128 + cout0] = pv;
    }
}

// ---------------------------------------------------------------------------
// Generic 3x3 MFMA conv, NHWC bf16 in/out, fp32 accum. Block = one out row.
// ---------------------------------------------------------------------------
template <int Cin, int Cout, int H, int W, int STRIDE, bool RELU>
__global__ __launch_bounds__(256) void k_convm(
    const unsigned short* __restrict__ xin, const unsigned short* __restrict__ wp,
    unsigned short* __restrict__ xout) {
  constexpr int OH = H / STRIDE, OW = W / STRIDE;
  constexpr int WI = W + 2;
  constexpr int WIH = (WI + 1) / 2;
  constexpr int NC = Cout / 16, NM = OW / 16;
  static_assert(NC % 4 == 0, "cout tiles divisible by 4 waves");
  constexpr int WCT = NC / 4, WMT = NM;
  const int g = blockIdx.y, oy = blockIdx.x;
  const unsigned short* ip = xin + (size_t)g * Cin * H * W;
  unsigned short* op = xout + (size_t)g * Cout * OH * OW;
  __shared__ __align__(16) unsigned short X[3][4][WI][8];
  const int wid = threadIdx.x >> 6, lane = threadIdx.x & 63;
  const int lm = lane & 15, lkg = lane >> 4, lk = lkg * 8;
  const int ct0 = wid * WCT;

  f32x4 acc[WCT * WMT];
#pragma unroll
  for (int t = 0; t < WCT * WMT; ++t) acc[t] = f32x4{0.f, 0.f, 0.f, 0.f};

  for (int cic = 0; cic < Cin / 32; ++cic) {
    __syncthreads();
    for (int c = threadIdx.x; c < 3 * 4 * WI; c += 256) {
      const int cig = c & 3, t2 = c >> 2;
      const int col = t2 % WI, r = t2 / WI;
      const int iy = oy * STRIDE - 1 + r, ix = col - 1;
      const int pcol = (STRIDE == 2) ? ((col >> 1) + (col & 1) * WIH) : col;
      u16x8 v = {0, 0, 0, 0, 0, 0, 0, 0};
      if ((unsigned)iy < (unsigned)H && (unsigned)ix < (unsigned)W)
        v = *(const u16x8*)&ip[(size_t)(iy * W + ix) * Cin + cic * 32 + cig * 8];
      *(u16x8*)&X[r][cig][pcol][0] = v;
    }
    __syncthreads();
#pragma unroll
    for (int tap = 0; tap < 9; ++tap) {
      const int ky = tap / 3, kx = tap % 3;
      bf16x8 bf[WMT];
#pragma unroll
      for (int j = 0; j < WMT; ++j) {
        const int m = j * 16 + lm;
        const int colr = (STRIDE == 2) ? (m + (kx >> 1) + (kx & 1) * WIH) : (m + kx);
        bf[j] = *(const bf16x8*)&X[ky][lkg][colr][0];
      }
#pragma unroll
      for (int i = 0; i < WCT; ++i) {
        const int cout = (ct0 + i) * 16 + lm;
        bf16x8 af = *(const bf16x8*)&wp[((cic * 9 + tap) * Cout + cout) * 32 + lk];
#pragma unroll
        for (int j = 0; j < WMT; ++j)
          acc[i * WMT + j] =
              __builtin_amdgcn_mfma_f32_16x16x32_bf16(af, bf[j], acc[i * WMT + j], 0, 0, 0);
      }
    }
  }
#pragma unroll
  for (int i = 0; i < WCT; ++i)
#pragma unroll
    for (int j = 0; j < WMT; ++j) {
      const int cout0 = (ct0 + i) * 16 + lkg * 4;
      const int m = j * 16 + lm;
      u16x4 pv;
#pragma unroll
      for (int r = 0; r < 4; ++r) {
        float f = acc[i * WMT + j][r];
        if (RELU) f = fmaxf(f, 0.f);
        pv[r] = f2b(f);
      }
      *(u16x4*)&op[(size_t)(oy * OW + m) * Cout + cout0] = pv;
    }
}

// ---------------------------------------------------------------------------
// Deconv (64->32, k=4, s=2, p=1) + relu, parity-split MFMA.
// in x4 NHWC (32,64,64); out x5 NHWC bf16 (64,128,32).
// ---------------------------------------------------------------------------
__global__ __launch_bounds__(256) void k_deconvm(
    const unsigned short* __restrict__ x4, const unsigned short* __restrict__ wp,
    unsigned short* __restrict__ x5) {
  const int g = blockIdx.y, mrow = blockIdx.x;
  const unsigned short* ip = x4 + (size_t)g * (2048 * 64);
  unsigned short* op = x5 + (size_t)g * (8192 * 32);
  constexpr int WI = 66;
  __shared__ __align__(16) unsigned short X[3][4][WI][8];
  const int wid = threadIdx.x >> 6, lane = threadIdx.x & 63;
  const int a = wid >> 1, b = wid & 1;
  const int lm = lane & 15, lkg = lane >> 4, lk = lkg * 8;
  f32x4 acc[8];
#pragma unroll
  for (int t = 0; t < 8; ++t) acc[t] = f32x4{0.f, 0.f, 0.f, 0.f};

  for (int cic = 0; cic < 2; ++cic) {
    __syncthreads();
    for (int c = threadIdx.x; c < 3 * 4 * WI; c += 256) {
      const int cig = c & 3, t2 = c >> 2;
      const int col = t2 % WI, r = t2 / WI;
      const int iy = mrow - 1 + r, ix = col - 1;
      u16x8 v = {0, 0, 0, 0, 0, 0, 0, 0};
      if ((unsigned)iy < 32u && (unsigned)ix < 64u)
        v = *(const u16x8*)&ip[(size_t)(iy * 64 + ix) * 64 + cic * 32 + cig * 8];
      *(u16x8*)&X[r][cig][col][0] = v;
    }
    __syncthreads();
#pragma unroll
    for (int u = 0; u < 2; ++u)
#pragma unroll
      for (int vv = 0; vv < 2; ++vv) {
        const int r = (a == 0) ? u : u + 1;
        const int ky = (a == 0) ? 2 * u : 2 * u + 1;
        const int s = (b == 0) ? vv : vv + 1;
        const int kx = (b == 0) ? 2 * vv : 2 * vv + 1;
        bf16x8 bf[4];
#pragma unroll
        for (int j = 0; j < 4; ++j)
          bf[j] = *(const bf16x8*)&X[r][lkg][j * 16 + lm + s][0];
#pragma unroll
        for (int i = 0; i < 2; ++i) {
          bf16x8 af =
              *(const bf16x8*)&wp[((((cic * 4 + ky) * 4 + kx) * 32) + i * 16 + lm) * 32 + lk];
#pragma unroll
          for (int j = 0; j < 4; ++j)
            acc[i * 4 + j] =
                __builtin_amdgcn_mfma_f32_16x16x32_bf16(af, bf[j], acc[i * 4 + j], 0, 0, 0);
        }
      }
  }
#pragma unroll
  for (int i = 0; i < 2; ++i)
#pragma unroll
    for (int j = 0; j < 4; ++j) {
      const int cout0 = i * 16 + lkg * 4;
      const int p = j * 16 + lm;
      const int orow = 2 * mrow + a, ocol = 2 * p + b;
      u16x4 pv;
#pragma unroll
      for (int r2 = 0; r2 < 4; ++r2) pv[r2] = f2b(fmaxf(acc[i * 4 + j][r2], 0.f));
      *(u16x4*)&op[(size_t)(orow * 128 + ocol) * 32 + cout0] = pv;
    }
}

// ---------------------------------------------------------------------------
// conv5 (32->1, 3x3): direct from L2, NHWC input, fp32 out. Thread per pixel.
// ---------------------------------------------------------------------------
__global__ __launch_bounds__(256) void k_conv5m(
    const unsigned short* __restrict__ x5, const float* __restrict__ w5,
    float* __restrict__ out) {
  const int g = blockIdx.y;
  const int pix = blockIdx.x * 256 + threadIdx.x;
  const int y = pix >> 7, x = pix & 127;
  const unsigned short* ip = x5 + (size_t)g * (8192 * 32);
  float s = 0.f;
#pragma unroll
  for (int t = 0; t < 9; ++t) {
    const int yy = y - 1 + t / 3, xx = x - 1 + t % 3;
    if ((unsigned)yy < 64u && (unsigned)xx < 128u) {
#pragma unroll
      for (int cg = 0; cg < 4; ++cg) {
        u16x8 v = *(const u16x8*)&ip[(size_t)(yy * 128 + xx) * 32 + cg * 8];
#pragma unroll
        for (int e = 0; e < 8; ++e) s += b2f(v[e]) * w5[(cg * 8 + e) * 9 + t];
      }
    }
  }
  out[(size_t)g * 8192 + pix] = s;
}

// ---------------------------------------------------------------------------
extern "C" void kernel_launch(void* const* d_in, const int* in_sizes, int n_in,
                              void* d_out, int out_size, void* d_ws, size_t ws_size,
                              hipStream_t stream) {
  const float* f1 = (const float*)d_in[0];
  const float* f2 = (const float*)d_in[1];
  const float* w1 = (const float*)d_in[2];
  const float* w2 = (const float*)d_in[3];
  const float* w3 = (const float*)d_in[4];
  const float* w4 = (const float*)d_in[5];
  const float* wd = (const float*)d_in[6];
  const float* w5 = (const float*)d_in[7];
  float* out = (float*)d_out;

  size_t off = 0;
  auto alloc = [&](size_t bytes) {
    void* p = (char*)d_ws + off;
    off += (bytes + 255) / 256 * 256;
    return p;
  };
  unsigned short* f1b = (unsigned short*)alloc(64 * 128 * 32 * 2);
  unsigned short* f2bp = (unsigned short*)alloc(64 * 128 * 32 * 2);
  unsigned short* w1p = (unsigned short*)alloc(2 * 9 * 96 * 32 * 2);
  unsigned short* w2p = (unsigned short*)alloc(3 * 9 * 128 * 32 * 2);
  unsigned short* w3p = (unsigned short*)alloc(4 * 9 * 128 * 32 * 2);
  unsigned short* w4p = (unsigned short*)alloc(4 * 9 * 64 * 32 * 2);
  unsigned short* wdp = (unsigned short*)alloc(2 * 16 * 32 * 32 * 2);
  unsigned short* z1b = (unsigned short*)alloc((size_t)64 * 128 * 96 * 2);   // bf16
  unsigned short* z2eb = (unsigned short*)alloc((size_t)76 * 140 * 96 * 2);  // bf16
  float* crow = (float*)alloc((size_t)13 * 8 * 128 * 96 * 4);
  float* ccol = (float*)alloc((size_t)13 * 64 * 8 * 96 * 4);
  float* ccor = (float*)alloc((size_t)NITEMS * 8 * 8 * 96 * 4);
  float* rtop = (float*)alloc((size_t)13 * 140 * 96 * 4);
  float* rbot = (float*)alloc((size_t)13 * 140 * 96 * 4);
  float* clft = (float*)alloc((size_t)13 * 76 * 96 * 4);
  float* crgt = (float*)alloc((size_t)13 * 76 * 96 * 4);
  float* kcorn = (float*)alloc((size_t)NITEMS * 4 * 96 * 4);
  const size_t wend = off;

  // Ping-pong slots: P holds x2 then x4; Q holds x3 then x5. 0.5 MiB each.
  const size_t perSlot = (size_t)128 * 2048 * 2;  // bytes
  int G = (int)((ws_size - wend) / (2 * perSlot));
  if (G > NITEMS) G = NITEMS;
  if (G < 1) G = 1;
  unsigned short* P = (unsigned short*)((char*)d_ws + wend);
  unsigned short* Q = (unsigned short*)((char*)d_ws + wend + (size_t)G * perSlot);

  k_prepf<<<32, 256, 0, stream>>>(f1, f1b);
  k_prepf<<<32, 256, 0, stream>>>(f2, f2bp);
  k_prep3x3<<<(96 * 64 * 9 + 255) / 256, 256, 0, stream>>>(w1, w1p, 96, 64);
  k_prep3x3<<<(128 * 96 * 9 + 255) / 256, 256, 0, stream>>>(w2, w2p, 128, 96);
  k_prep3x3<<<(128 * 128 * 9 + 255) / 256, 256, 0, stream>>>(w3, w3p, 128, 128);
  k_prep3x3<<<(64 * 128 * 9 + 255) / 256, 256, 0, stream>>>(w4, w4p, 64, 128);
  k_prepwd<<<(32 * 64 * 16 + 255) / 256, 256, 0, stream>>>(wd, wdp);

  k_z1<<<32, 256, 0, stream>>>(f1b, w1p, z1b);
  k_z2e<<<76, 256, 0, stream>>>(f2bp, w1p, z2eb);
  k_crow<<<91, 256, 0, stream>>>(f1b, w1p, crow);
  k_ccol<<<13, 256, 0, stream>>>(f1b, w1p, ccol);
  k_ccorner<<<(NITEMS * 64 * 96 + 255) / 256, 256, 0, stream>>>(f1b, w1p, ccor);
  k_bcorr_rows<<<(13 * 140 * 96 + 255) / 256, 256, 0, stream>>>(f2bp, w1p, rtop, rbot);
  k_bcorr_cols<<<(13 * 76 * 96 + 255) / 256, 256, 0, stream>>>(f2bp, w1p, clft, crgt);
  k_bcorr_corn<<<(NITEMS * 4 * 96 + 255) / 256, 256, 0, stream>>>(f2bp, w1p, kcorn);

  for (int base = 0; base < NITEMS; base += G) {
    const int cnt = (NITEMS - base < G) ? (NITEMS - base) : G;
    // x2 = relu(conv2(x1_onthefly))      : P
    k_conv2f<<<dim3(32, cnt), 256, 0, stream>>>(z1b, z2eb, crow, ccol, ccor, rtop, rbot,
                                                clft, crgt, kcorn, w2p, P, base);
    // x3 = relu(conv3(x2))               : Q
    k_convm<128, 128, 32, 64, 1, true><<<dim3(32, cnt), 256, 0, stream>>>(P, w3p, Q);
    // x4 = relu(conv4(x3))               : P (x2 dead)
    k_convm<128, 64, 32, 64, 1, true><<<dim3(32, cnt), 256, 0, stream>>>(Q, w4p, P);
    // x5 = relu(deconv(x4))              : Q (x3 dead)
    k_deconvm<<<dim3(32, cnt), 256, 0, stream>>>(P, wdp, Q);
    // cost = conv5(x5)                   : out
    k_conv5m<<<dim3(32, cnt), 256, 0, stream>>>(Q, w5, out + (size_t)base * 8192);
  }
}

// Round 17
// 684.204 us; speedup vs baseline: 1.3207x; 1.3207x over previous
//
#include <hip/hip_runtime.h>

#define NITEMS 169

typedef __attribute__((ext_vector_type(8))) __bf16 bf16x8;
typedef __attribute__((ext_vector_type(4))) float f32x4;
typedef __attribute__((ext_vector_type(8))) unsigned short u16x8;
typedef __attribute__((ext_vector_type(4))) unsigned short u16x4;

__device__ __forceinline__ unsigned short f2b(float x) {
  union { float f; unsigned u; } v; v.f = x;
  unsigned r = v.u + 0x7fffu + ((v.u >> 16) & 1u);
  return (unsigned short)(r >> 16);
}
// HW RNE float->bf16 (identical result for finite values)
__device__ __forceinline__ unsigned short f2b2(float x) {
  __bf16 b = (__bf16)x;
  union { __bf16 b; unsigned short u; } v; v.b = b;
  return v.u;
}
__device__ __forceinline__ float b2f(unsigned short u) {
  union { unsigned u; float f; } v; v.u = ((unsigned)u) << 16;
  return v.f;
}

// f32 NCHW (32,64,128) -> bf16 NHWC (64,128,32)
__global__ __launch_bounds__(256) void k_prepf(const float* __restrict__ f,
                                               unsigned short* __restrict__ fb) {
  const int pix = blockIdx.x * 256 + threadIdx.x;
  const int y = pix >> 7, x = pix & 127;
#pragma unroll
  for (int c = 0; c < 32; ++c)
    fb[(size_t)pix * 32 + c] = f2b(f[(c * 64 + y) * 128 + x]);
}

// Pack 3x3 conv weights [Cout][Cin][3][3] f32 -> [cic][tap][cout][32ci] bf16
__global__ void k_prep3x3(const float* __restrict__ w, unsigned short* __restrict__ wp,
                          int Cout, int Cin) {
  int i = blockIdx.x * 256 + threadIdx.x;
  if (i >= Cout * Cin * 9) return;
  int kx = i % 3, t = i / 3;
  int ky = t % 3; t /= 3;
  int cin = t % Cin, cout = t / Cin;
  int tap = ky * 3 + kx;
  wp[(((cin >> 5) * 9 + tap) * Cout + cout) * 32 + (cin & 31)] = f2b(w[i]);
}

// Pack deconv weights [32][64][4][4] f32 -> [cic][ky][kx][cout][32ci] bf16
__global__ void k_prepwd(const float* __restrict__ w, unsigned short* __restrict__ wp) {
  int i = blockIdx.x * 256 + threadIdx.x;
  if (i >= 32 * 64 * 16) return;
  int kx = i & 3, ky = (i >> 2) & 3, ci = (i >> 4) & 63, cout = i >> 10;
  wp[(((((ci >> 5) * 4 + ky) * 4 + kx) * 32) + cout) * 32 + (ci & 31)] = f2b(w[i]);
}

// ---------------------------------------------------------------------------
// Z1 = conv3x3(f1, w1[:, 0:32]) on (64,128), no relu. NHWC bf16 out
// (1.5 MB -> L2-resident everywhere).
// ---------------------------------------------------------------------------
__global__ __launch_bounds__(256) void k_z1(
    const unsigned short* __restrict__ f1b, const unsigned short* __restrict__ wp,
    unsigned short* __restrict__ z1) {
  const int oy0 = blockIdx.x * 2;
  constexpr int WI = 130;
  __shared__ __align__(16) unsigned short X[4][4][WI][8];
  const int wid = threadIdx.x >> 6, lane = threadIdx.x & 63;
  const int lm = lane & 15, lkg = lane >> 4, lk = lkg * 8;

  f32x4 acc[24];
#pragma unroll
  for (int t = 0; t < 24; ++t) acc[t] = f32x4{0.f, 0.f, 0.f, 0.f};

  for (int c = threadIdx.x; c < 4 * 4 * WI; c += 256) {
    const int cig = c & 3, t2 = c >> 2;
    const int col = t2 % WI, r = t2 / WI;
    const int iy = oy0 - 1 + r, ix = col - 1;
    u16x8 v = {0, 0, 0, 0, 0, 0, 0, 0};
    if ((unsigned)iy < 64u && (unsigned)ix < 128u)
      v = *(const u16x8*)&f1b[(size_t)(iy * 128 + ix) * 32 + cig * 8];
    *(u16x8*)&X[r][cig][col][0] = v;
  }
  __syncthreads();
#pragma unroll
  for (int tap = 0; tap < 9; ++tap) {
    const int ky = tap / 3, kx = tap % 3;
    bf16x8 bf[4];
#pragma unroll
    for (int j = 0; j < 4; ++j) {
      const int mt = wid * 4 + j, rw = mt >> 3, mtx = mt & 7;
      bf[j] = *(const bf16x8*)&X[rw + ky][lkg][mtx * 16 + lm + kx][0];
    }
#pragma unroll
    for (int i = 0; i < 6; ++i) {
      bf16x8 af = *(const bf16x8*)&wp[((0 * 9 + tap) * 96 + i * 16 + lm) * 32 + lk];
#pragma unroll
      for (int j = 0; j < 4; ++j)
        acc[i * 4 + j] =
            __builtin_amdgcn_mfma_f32_16x16x32_bf16(af, bf[j], acc[i * 4 + j], 0, 0, 0);
    }
  }
#pragma unroll
  for (int i = 0; i < 6; ++i)
#pragma unroll
    for (int j = 0; j < 4; ++j) {
      const int mt = wid * 4 + j, rw = mt >> 3, mtx = mt & 7;
      const int cout0 = i * 16 + lkg * 4;
      const int m = mtx * 16 + lm;
      u16x4 pv;
#pragma unroll
      for (int r = 0; r < 4; ++r) pv[r] = f2b(acc[i * 4 + j][r]);
      *(u16x4*)&z1[(size_t)((oy0 + rw) * 128 + m) * 96 + cout0] = pv;
    }
}

// ---------------------------------------------------------------------------
// Z2ext = conv3x3(zero-padded f2, w1[:, 32:64]) on (76,140). NHWC bf16
// (2.0 MB -> L2-resident).
// ---------------------------------------------------------------------------
__global__ __launch_bounds__(256) void k_z2e(
    const unsigned short* __restrict__ f2b_, const unsigned short* __restrict__ wp,
    unsigned short* __restrict__ z2e) {
  const int u = blockIdx.x;  // 0..75
  constexpr int WI = 194;
  __shared__ __align__(16) unsigned short X[3][4][WI][8];
  const int wid = threadIdx.x >> 6, lane = threadIdx.x & 63;
  const int lm = lane & 15, lkg = lane >> 4, lk = lkg * 8;

  f32x4 acc[18];
#pragma unroll
  for (int t = 0; t < 18; ++t) acc[t] = f32x4{0.f, 0.f, 0.f, 0.f};

  for (int c = threadIdx.x; c < 3 * 4 * WI; c += 256) {
    const int cig = c & 3, t2 = c >> 2;
    const int col = t2 % WI, r = t2 / WI;
    const int iy = u + r - 7, ix = col - 7;
    u16x8 v = {0, 0, 0, 0, 0, 0, 0, 0};
    if ((unsigned)iy < 64u && (unsigned)ix < 128u)
      v = *(const u16x8*)&f2b_[(size_t)(iy * 128 + ix) * 32 + cig * 8];
    *(u16x8*)&X[r][cig][col][0] = v;
  }
  __syncthreads();
#pragma unroll
  for (int tap = 0; tap < 9; ++tap) {
    const int ky = tap / 3, kx = tap % 3;
    bf16x8 bf[3];
#pragma unroll
    for (int j = 0; j < 3; ++j) {
      const int mt = wid * 3 + j;
      bf[j] = *(const bf16x8*)&X[ky][lkg][mt * 16 + lm + kx][0];
    }
#pragma unroll
    for (int i = 0; i < 6; ++i) {
      bf16x8 af = *(const bf16x8*)&wp[((1 * 9 + tap) * 96 + i * 16 + lm) * 32 + lk];
#pragma unroll
      for (int j = 0; j < 3; ++j)
        acc[i * 3 + j] =
            __builtin_amdgcn_mfma_f32_16x16x32_bf16(af, bf[j], acc[i * 3 + j], 0, 0, 0);
    }
  }
#pragma unroll
  for (int i = 0; i < 6; ++i)
#pragma unroll
    for (int j = 0; j < 3; ++j) {
      const int v = (wid * 3 + j) * 16 + lm;
      if (v < 140) {
        const int cout0 = i * 16 + lkg * 4;
        u16x4 pv;
#pragma unroll
        for (int r = 0; r < 4; ++r) pv[r] = f2b(acc[i * 3 + j][r]);
        *(u16x4*)&z2e[(size_t)(u * 140 + v) * 96 + cout0] = pv;
      }
    }
}

// ---------------------------------------------------------------------------
// Crow[dyi] = conv3x3(f1 * row-band(dy), w1a); fp32 out [13][8][128][96].
// ---------------------------------------------------------------------------
__global__ __launch_bounds__(256) void k_crow(
    const unsigned short* __restrict__ f1b, const unsigned short* __restrict__ wp,
    float* __restrict__ crow) {
  const int dyi = blockIdx.x / 7, r = blockIdx.x % 7;
  const int dy = dyi - 6;
  const int ady = dy < 0 ? -dy : dy;
  if (dy == 0 || r >= ady + 1) return;
  const int rowlo = dy > 0 ? 63 - dy : 0;
  const int oy = rowlo + r;
  constexpr int WI = 130;
  __shared__ __align__(16) unsigned short X[3][4][WI][8];
  const int wid = threadIdx.x >> 6, lane = threadIdx.x & 63;
  const int lm = lane & 15, lkg = lane >> 4, lk = lkg * 8;

  f32x4 acc[12];
#pragma unroll
  for (int t = 0; t < 12; ++t) acc[t] = f32x4{0.f, 0.f, 0.f, 0.f};

  for (int c = threadIdx.x; c < 3 * 4 * WI; c += 256) {
    const int cig = c & 3, t2 = c >> 2;
    const int col = t2 % WI, rr = t2 / WI;
    const int iy = oy - 1 + rr, ix = col - 1;
    const bool band = dy > 0 ? (iy >= 64 - dy) : (iy < -dy);
    u16x8 v = {0, 0, 0, 0, 0, 0, 0, 0};
    if (band && (unsigned)iy < 64u && (unsigned)ix < 128u)
      v = *(const u16x8*)&f1b[(size_t)(iy * 128 + ix) * 32 + cig * 8];
    *(u16x8*)&X[rr][cig][col][0] = v;
  }
  __syncthreads();
#pragma unroll
  for (int tap = 0; tap < 9; ++tap) {
    const int ky = tap / 3, kx = tap % 3;
    bf16x8 bf[2];
#pragma unroll
    for (int j = 0; j < 2; ++j)
      bf[j] = *(const bf16x8*)&X[ky][lkg][(wid * 2 + j) * 16 + lm + kx][0];
#pragma unroll
    for (int i = 0; i < 6; ++i) {
      bf16x8 af = *(const bf16x8*)&wp[((0 * 9 + tap) * 96 + i * 16 + lm) * 32 + lk];
#pragma unroll
      for (int j = 0; j < 2; ++j)
        acc[i * 2 + j] =
            __builtin_amdgcn_mfma_f32_16x16x32_bf16(af, bf[j], acc[i * 2 + j], 0, 0, 0);
    }
  }
#pragma unroll
  for (int i = 0; i < 6; ++i)
#pragma unroll
    for (int j = 0; j < 2; ++j) {
      const int cout0 = i * 16 + lkg * 4;
      const int m = (wid * 2 + j) * 16 + lm;
      *(f32x4*)&crow[(size_t)((dyi * 8 + r) * 128 + m) * 96 + cout0] = acc[i * 2 + j];
    }
}

// ---------------------------------------------------------------------------
// Ccol[dxi] = conv3x3(f1 * col-band(dx), w1a); fp32 out [13][64][8][96].
// ---------------------------------------------------------------------------
__global__ __launch_bounds__(256) void k_ccol(
    const unsigned short* __restrict__ f1b, const unsigned short* __restrict__ wp,
    float* __restrict__ ccol) {
  const int dxi = blockIdx.x;
  const int dx = dxi - 6;
  const int adx = dx < 0 ? -dx : dx;
  if (dx == 0) return;
  const int ccnt = adx + 1;
  const int collo = dx > 0 ? 127 - dx : 0;
  __shared__ __align__(16) unsigned short X2[9][66][32];
  const int wid = threadIdx.x >> 6, lane = threadIdx.x & 63;
  const int lm = lane & 15, lkg = lane >> 4, lk = lkg * 8;

  for (int t = threadIdx.x; t < 9 * 66 * 4; t += 256) {
    const int cig = t & 3, pos = t >> 2;
    const int rr = pos % 66, cc = pos / 66;
    const int iy = rr - 1, ix = collo - 1 + cc;
    const bool band = dx > 0 ? (ix >= 128 - dx) : (ix < -dx);
    u16x8 v = {0, 0, 0, 0, 0, 0, 0, 0};
    if (band && (unsigned)iy < 64u && (unsigned)ix < 128u)
      v = *(const u16x8*)&f1b[(size_t)(iy * 128 + ix) * 32 + cig * 8];
    *(u16x8*)&X2[cc][rr][cig * 8] = v;
  }
  __syncthreads();
  for (int c = 0; c < ccnt; ++c) {
    f32x4 acc[6];
#pragma unroll
    for (int i = 0; i < 6; ++i) acc[i] = f32x4{0.f, 0.f, 0.f, 0.f};
#pragma unroll
    for (int tap = 0; tap < 9; ++tap) {
      const int ky = tap / 3, kx = tap % 3;
      bf16x8 bf = *(const bf16x8*)&X2[c + kx][wid * 16 + lm + ky][lk];
#pragma unroll
      for (int i = 0; i < 6; ++i) {
        bf16x8 af = *(const bf16x8*)&wp[((0 * 9 + tap) * 96 + i * 16 + lm) * 32 + lk];
        acc[i] = __builtin_amdgcn_mfma_f32_16x16x32_bf16(af, bf, acc[i], 0, 0, 0);
      }
    }
    const int y = wid * 16 + lm;
#pragma unroll
    for (int i = 0; i < 6; ++i) {
      const int cout0 = i * 16 + lkg * 4;
      *(f32x4*)&ccol[(size_t)((dxi * 64 + y) * 8 + c) * 96 + cout0] = acc[i];
    }
  }
}

// ---------------------------------------------------------------------------
// Vectorized bf16 dot over 32 channels.
// ---------------------------------------------------------------------------
__device__ __forceinline__ float dot32(const unsigned short* __restrict__ xv,
                                       const unsigned short* __restrict__ wv) {
  float s = 0.f;
#pragma unroll
  for (int cg = 0; cg < 4; ++cg) {
    u16x8 a = *(const u16x8*)&xv[cg * 8];
    u16x8 b = *(const u16x8*)&wv[cg * 8];
#pragma unroll
    for (int e = 0; e < 8; ++e) s += b2f(a[e]) * b2f(b[e]);
  }
  return s;
}

// ---------------------------------------------------------------------------
// Ccorner: one thread per (item, r, c, co). 169*8*8*96 outputs.
// ---------------------------------------------------------------------------
__global__ __launch_bounds__(256) void k_ccorner(
    const unsigned short* __restrict__ f1b, const unsigned short* __restrict__ w1p,
    float* __restrict__ ccor) {
  const int idx = blockIdx.x * 256 + threadIdx.x;
  if (idx >= NITEMS * 64 * 96) return;
  const int co = idx % 96, t = idx / 96;
  const int c = t & 7, r = (t >> 3) & 7, item = t >> 6;
  const int dx = item / 13 - 6, dy = item % 13 - 6;
  if (dx == 0 || dy == 0) return;
  const int ady = dy < 0 ? -dy : dy, adx = dx < 0 ? -dx : dx;
  if (r >= ady + 1 || c >= adx + 1) return;
  const int rowlo = dy > 0 ? 63 - dy : 0;
  const int collo = dx > 0 ? 127 - dx : 0;
  const int oy = rowlo + r, ox = collo + c;
  float acc = 0.f;
#pragma unroll
  for (int ky = 0; ky < 3; ++ky)
#pragma unroll
    for (int kx = 0; kx < 3; ++kx) {
      const int iy = oy - 1 + ky, ix = ox - 1 + kx;
      const bool rb = dy > 0 ? (iy >= 64 - dy) : (iy < -dy);
      const bool cb = dx > 0 ? (ix >= 128 - dx) : (ix < -dx);
      if (rb && cb && (unsigned)iy < 64u && (unsigned)ix < 128u)
        acc += dot32(&f1b[(size_t)(iy * 128 + ix) * 32],
                     &w1p[((ky * 3 + kx) * 96 + co) * 32]);
    }
  ccor[(size_t)(((item * 8 + r) * 8 + c) * 96) + co] = acc;
}

// rtop/rbot[dyi][v][co]: one thread per (dyi,v,co). 13*140*96 outputs.
__global__ __launch_bounds__(256) void k_bcorr_rows(
    const unsigned short* __restrict__ f2bp, const unsigned short* __restrict__ w1p,
    float* __restrict__ rtop, float* __restrict__ rbot) {
  const int idx = blockIdx.x * 256 + threadIdx.x;
  if (idx >= 13 * 140 * 96) return;
  const int co = idx % 96, t = idx / 96;
  const int v = t % 140, dyi = t / 140;
  const int dy = dyi - 6;
  const int rt = dy - 1, rb = 64 + dy;
  float at = 0.f, ab = 0.f;
#pragma unroll
  for (int kx = 0; kx < 3; ++kx) {
    const int x2 = v - 7 + kx;
    if ((unsigned)x2 >= 128u) continue;
    if ((unsigned)rt < 64u)
      at += dot32(&f2bp[(size_t)(rt * 128 + x2) * 32],
                  &w1p[((9 + 0 + kx) * 96 + co) * 32]);
    if ((unsigned)rb < 64u)
      ab += dot32(&f2bp[(size_t)(rb * 128 + x2) * 32],
                  &w1p[((9 + 6 + kx) * 96 + co) * 32]);
  }
  rtop[idx] = at;
  rbot[idx] = ab;
}

// clft/crgt[dxi][u][co]: one thread per (dxi,u,co). 13*76*96 outputs.
__global__ __launch_bounds__(256) void k_bcorr_cols(
    const unsigned short* __restrict__ f2bp, const unsigned short* __restrict__ w1p,
    float* __restrict__ clft, float* __restrict__ crgt) {
  const int idx = blockIdx.x * 256 + threadIdx.x;
  if (idx >= 13 * 76 * 96) return;
  const int co = idx % 96, t = idx / 96;
  const int u = t % 76, dxi = t / 76;
  const int dx = dxi - 6;
  const int cl = dx - 1, cr = 128 + dx;
  float al = 0.f, ar = 0.f;
#pragma unroll
  for (int ky = 0; ky < 3; ++ky) {
    const int y2 = u - 7 + ky;
    if ((unsigned)y2 >= 64u) continue;
    if ((unsigned)cl < 128u)
      al += dot32(&f2bp[(size_t)(y2 * 128 + cl) * 32],
                  &w1p[((9 + ky * 3 + 0) * 96 + co) * 32]);
    if ((unsigned)cr < 128u)
      ar += dot32(&f2bp[(size_t)(y2 * 128 + cr) * 32],
                  &w1p[((9 + ky * 3 + 2) * 96 + co) * 32]);
  }
  clft[idx] = al;
  crgt[idx] = ar;
}

// kcorn[item][corner][co]: one thread per output. 169*4*96 outputs.
__global__ __launch_bounds__(256) void k_bcorr_corn(
    const unsigned short* __restrict__ f2bp, const unsigned short* __restrict__ w1p,
    float* __restrict__ kcorn) {
  const int idx = blockIdx.x * 256 + threadIdx.x;
  if (idx >= NITEMS * 4 * 96) return;
  const int co = idx % 96, t = idx / 96;
  const int corner = t % 4, item = t / 4;
  const int dx = item / 13 - 6, dy = item % 13 - 6;
  const int row = (corner < 2) ? dy - 1 : 64 + dy;
  const int col = (corner & 1) ? 128 + dx : dx - 1;
  const int ky = (corner < 2) ? 0 : 2;
  const int kx = (corner & 1) ? 2 : 0;
  float acc = 0.f;
  if ((unsigned)row < 64u && (unsigned)col < 128u)
    acc = dot32(&f2bp[(size_t)(row * 128 + col) * 32],
                &w1p[((9 + ky * 3 + kx) * 96 + co) * 32]);
  kcorn[idx] = acc;
}

// ---------------------------------------------------------------------------
// Full correction formula (8 channels at c0), bf16 z1/z2e terms.
// Only for correction pixels.
// ---------------------------------------------------------------------------
struct ItemGeo {
  int item, dx, dy, dyi, dxi, rowlo, rowhi, collo, colhi;
};

__device__ __forceinline__ u16x8 x1_fuse8(
    const unsigned short* __restrict__ z1b, const unsigned short* __restrict__ z2eb,
    const float* __restrict__ crow, const float* __restrict__ ccol,
    const float* __restrict__ ccor, const float* __restrict__ rtop,
    const float* __restrict__ rbot, const float* __restrict__ clft,
    const float* __restrict__ crgt, const float* __restrict__ kcorn,
    const ItemGeo& gm, int y, int px, int c0) {
  const bool inrow = (y >= gm.rowlo) && (y < gm.rowhi);
  const bool incol = (px >= gm.collo) && (px < gm.colhi);
  const int vrow = y + gm.dy + 6;
  const int v = px + gm.dx + 6;
  u16x8 a = *(const u16x8*)&z1b[(size_t)(y * 128 + px) * 96 + c0];
  u16x8 b = *(const u16x8*)&z2eb[(size_t)(vrow * 140 + v) * 96 + c0];
  u16x8 o;
#pragma unroll
  for (int h = 0; h < 2; ++h) {
    const int cc = c0 + h * 4;
    f32x4 s;
#pragma unroll
    for (int e = 0; e < 4; ++e) s[e] = b2f(a[h * 4 + e]) + b2f(b[h * 4 + e]);
    if (inrow)
      s -= *(const f32x4*)&crow[(size_t)((gm.dyi * 8 + y - gm.rowlo) * 128 + px) * 96 + cc];
    if (incol) {
      s -= *(const f32x4*)&ccol[(size_t)((gm.dxi * 64 + y) * 8 + px - gm.collo) * 96 + cc];
      if (inrow)
        s += *(const f32x4*)&ccor[(size_t)(((gm.item * 8 + y - gm.rowlo) * 8) + px - gm.collo) * 96 + cc];
    }
    if (y == 0) s -= *(const f32x4*)&rtop[(size_t)(gm.dyi * 140 + v) * 96 + cc];
    if (y == 63) s -= *(const f32x4*)&rbot[(size_t)(gm.dyi * 140 + v) * 96 + cc];
    if (px == 0) s -= *(const f32x4*)&clft[(size_t)(gm.dxi * 76 + vrow) * 96 + cc];
    if (px == 127) s -= *(const f32x4*)&crgt[(size_t)(gm.dxi * 76 + vrow) * 96 + cc];
    if (y == 0 && px == 0) s += *(const f32x4*)&kcorn[(size_t)gm.item * 384 + 0 * 96 + cc];
    if (y == 0 && px == 127) s += *(const f32x4*)&kcorn[(size_t)gm.item * 384 + 1 * 96 + cc];
    if (y == 63 && px == 0) s += *(const f32x4*)&kcorn[(size_t)gm.item * 384 + 2 * 96 + cc];
    if (y == 63 && px == 127) s += *(const f32x4*)&kcorn[(size_t)gm.item * 384 + 3 * 96 + cc];
#pragma unroll
    for (int e = 0; e < 4; ++e) o[h * 4 + e] = f2b(fmaxf(s[e], 0.f));
  }
  return o;
}

// ---------------------------------------------------------------------------
// Fused assemble+conv2 (R12 structure: strided predicated staging, 2
// barriers per cic) with bf16 L2-resident z1/z2e terms.
// Out x2 NHWC bf16 (32,64,128).
// ---------------------------------------------------------------------------
__global__ __launch_bounds__(256) void k_conv2f(
    const unsigned short* __restrict__ z1b, const unsigned short* __restrict__ z2eb,
    const float* __restrict__ crow, const float* __restrict__ ccol,
    const float* __restrict__ ccor, const float* __restrict__ rtop,
    const float* __restrict__ rbot, const float* __restrict__ clft,
    const float* __restrict__ crgt, const float* __restrict__ kcorn,
    const unsigned short* __restrict__ wp, unsigned short* __restrict__ x2,
    int base) {
  constexpr int WI = 130, WIH = 65;
  const int g = blockIdx.y, oy = blockIdx.x;
  const int item = base + g;
  ItemGeo gm;
  gm.item = item;
  gm.dx = item / 13 - 6;
  gm.dy = item % 13 - 6;
  gm.dyi = gm.dy + 6;
  gm.dxi = gm.dx + 6;
  {
    const int ady = gm.dy < 0 ? -gm.dy : gm.dy, adx = gm.dx < 0 ? -gm.dx : gm.dx;
    gm.rowlo = gm.dy > 0 ? 63 - gm.dy : 0;
    gm.rowhi = gm.rowlo + (gm.dy ? ady + 1 : 0);
    gm.collo = gm.dx > 0 ? 127 - gm.dx : 0;
    gm.colhi = gm.collo + (gm.dx ? adx + 1 : 0);
  }
  unsigned short* op = x2 + (size_t)g * (128 * 2048);
  __shared__ __align__(16) unsigned short X[3][4][WI][8];
  const int wid = threadIdx.x >> 6, lane = threadIdx.x & 63;
  const int lm = lane & 15, lkg = lane >> 4, lk = lkg * 8;
  const int ct0 = wid * 2;

  f32x4 acc[8];
#pragma unroll
  for (int t = 0; t < 8; ++t) acc[t] = f32x4{0.f, 0.f, 0.f, 0.f};

  for (int cic = 0; cic < 3; ++cic) {
    __syncthreads();
    for (int c = threadIdx.x; c < 3 * 4 * WI; c += 256) {
      const int cig = c & 3, t2 = c >> 2;
      const int col = t2 % WI, r = t2 / WI;
      const int iy = oy * 2 - 1 + r, ix = col - 1;
      const int pcol = (col >> 1) + (col & 1) * WIH;
      u16x8 v = {0, 0, 0, 0, 0, 0, 0, 0};
      if ((unsigned)iy < 64u && (unsigned)ix < 128u) {
        const bool rowc = (iy >= gm.rowlo && iy < gm.rowhi) || iy == 0 || iy == 63;
        const bool colc = (ix >= gm.collo && ix < gm.colhi) || ix == 0 || ix == 127;
        if (rowc || colc) {
          v = x1_fuse8(z1b, z2eb, crow, ccol, ccor, rtop, rbot, clft, crgt, kcorn,
                       gm, iy, ix, cic * 32 + cig * 8);
        } else {
          const unsigned short* p1 = &z1b[(size_t)(iy * 128 + ix) * 96 + cic * 32 + cig * 8];
          const unsigned short* p2 =
              &z2eb[(size_t)((iy + gm.dy + 6) * 140 + (ix + gm.dx + 6)) * 96 + cic * 32 + cig * 8];
          u16x8 a = *(const u16x8*)p1;
          u16x8 b = *(const u16x8*)p2;
#pragma unroll
          for (int e = 0; e < 8; ++e)
            v[e] = f2b2(fmaxf(b2f(a[e]) + b2f(b[e]), 0.f));
        }
      }
      *(u16x8*)&X[r][cig][pcol][0] = v;
    }
    __syncthreads();
#pragma unroll
    for (int tap = 0; tap < 9; ++tap) {
      const int ky = tap / 3, kx = tap % 3;
      bf16x8 bf[4];
#pragma unroll
      for (int j = 0; j < 4; ++j) {
        const int m = j * 16 + lm;
        const int colr = m + (kx >> 1) + (kx & 1) * WIH;
        bf[j] = *(const bf16x8*)&X[ky][lkg][colr][0];
      }
#pragma unroll
      for (int i = 0; i < 2; ++i) {
        const int cout = (ct0 + i) * 16 + lm;
        bf16x8 af = *(const bf16x8*)&wp[((cic * 9 + tap) * 128 + cout) * 32 + lk];
#pragma unroll
        for (int j = 0; j < 4; ++j)
          acc[i * 4 + j] =
              __builtin_amdgcn_mfma_f32_16x16x32_bf16(af, bf[j], acc[i * 4 + j], 0, 0, 0);
      }
    }
  }
#pragma unroll
  for (int i = 0; i < 2; ++i)
#pragma unroll
    for (int j = 0; j < 4; ++j) {
      const int cout0 = (ct0 + i) * 16 + lkg * 4;
      const int m = j * 16 + lm;
      u16x4 pv;
#pragma unroll
      for (int r = 0; r < 4; ++r) pv[r] = f2b(fmaxf(acc[i * 4 + j][r], 0.f));
      *(u16x4*)&op[(size_t)(oy * 64 + m) * 128 + cout0] = pv;
    }
}

// ---------------------------------------------------------------------------
// Generic 3x3 MFMA conv, NHWC bf16 in/out, fp32 accum. Block = one out row.
// ---------------------------------------------------------------------------
template <int Cin, int Cout, int H, int W, int STRIDE, bool RELU>
__global__ __launch_bounds__(256) void k_convm(
    const unsigned short* __restrict__ xin, const unsigned short* __restrict__ wp,
    unsigned short* __restrict__ xout) {
  constexpr int OH = H / STRIDE, OW = W / STRIDE;
  constexpr int WI = W + 2;
  constexpr int WIH = (WI + 1) / 2;
  constexpr int NC = Cout / 16, NM = OW / 16;
  static_assert(NC % 4 == 0, "cout tiles divisible by 4 waves");
  constexpr int WCT = NC / 4, WMT = NM;
  const int g = blockIdx.y, oy = blockIdx.x;
  const unsigned short* ip = xin + (size_t)g * Cin * H * W;
  unsigned short* op = xout + (size_t)g * Cout * OH * OW;
  __shared__ __align__(16) unsigned short X[3][4][WI][8];
  const int wid = threadIdx.x >> 6, lane = threadIdx.x & 63;
  const int lm = lane & 15, lkg = lane >> 4, lk = lkg * 8;
  const int ct0 = wid * WCT;

  f32x4 acc[WCT * WMT];
#pragma unroll
  for (int t = 0; t < WCT * WMT; ++t) acc[t] = f32x4{0.f, 0.f, 0.f, 0.f};

  for (int cic = 0; cic < Cin / 32; ++cic) {
    __syncthreads();
    for (int c = threadIdx.x; c < 3 * 4 * WI; c += 256) {
      const int cig = c & 3, t2 = c >> 2;
      const int col = t2 % WI, r = t2 / WI;
      const int iy = oy * STRIDE - 1 + r, ix = col - 1;
      const int pcol = (STRIDE == 2) ? ((col >> 1) + (col & 1) * WIH) : col;
      u16x8 v = {0, 0, 0, 0, 0, 0, 0, 0};
      if ((unsigned)iy < (unsigned)H && (unsigned)ix < (unsigned)W)
        v = *(const u16x8*)&ip[(size_t)(iy * W + ix) * Cin + cic * 32 + cig * 8];
      *(u16x8*)&X[r][cig][pcol][0] = v;
    }
    __syncthreads();
#pragma unroll
    for (int tap = 0; tap < 9; ++tap) {
      const int ky = tap / 3, kx = tap % 3;
      bf16x8 bf[WMT];
#pragma unroll
      for (int j = 0; j < WMT; ++j) {
        const int m = j * 16 + lm;
        const int colr = (STRIDE == 2) ? (m + (kx >> 1) + (kx & 1) * WIH) : (m + kx);
        bf[j] = *(const bf16x8*)&X[ky][lkg][colr][0];
      }
#pragma unroll
      for (int i = 0; i < WCT; ++i) {
        const int cout = (ct0 + i) * 16 + lm;
        bf16x8 af = *(const bf16x8*)&wp[((cic * 9 + tap) * Cout + cout) * 32 + lk];
#pragma unroll
        for (int j = 0; j < WMT; ++j)
          acc[i * WMT + j] =
              __builtin_amdgcn_mfma_f32_16x16x32_bf16(af, bf[j], acc[i * WMT + j], 0, 0, 0);
      }
    }
  }
#pragma unroll
  for (int i = 0; i < WCT; ++i)
#pragma unroll
    for (int j = 0; j < WMT; ++j) {
      const int cout0 = (ct0 + i) * 16 + lkg * 4;
      const int m = j * 16 + lm;
      u16x4 pv;
#pragma unroll
      for (int r = 0; r < 4; ++r) {
        float f = acc[i * WMT + j][r];
        if (RELU) f = fmaxf(f, 0.f);
        pv[r] = f2b(f);
      }
      *(u16x4*)&op[(size_t)(oy * OW + m) * Cout + cout0] = pv;
    }
}

// ---------------------------------------------------------------------------
// Deconv (64->32, k=4, s=2, p=1) + relu, parity-split MFMA.
// in x4 NHWC (32,64,64); out x5 NHWC bf16 (64,128,32).
// ---------------------------------------------------------------------------
__global__ __launch_bounds__(256) void k_deconvm(
    const unsigned short* __restrict__ x4, const unsigned short* __restrict__ wp,
    unsigned short* __restrict__ x5) {
  const int g = blockIdx.y, mrow = blockIdx.x;
  const unsigned short* ip = x4 + (size_t)g * (2048 * 64);
  unsigned short* op = x5 + (size_t)g * (8192 * 32);
  constexpr int WI = 66;
  __shared__ __align__(16) unsigned short X[3][4][WI][8];
  const int wid = threadIdx.x >> 6, lane = threadIdx.x & 63;
  const int a = wid >> 1, b = wid & 1;
  const int lm = lane & 15, lkg = lane >> 4, lk = lkg * 8;
  f32x4 acc[8];
#pragma unroll
  for (int t = 0; t < 8; ++t) acc[t] = f32x4{0.f, 0.f, 0.f, 0.f};

  for (int cic = 0; cic < 2; ++cic) {
    __syncthreads();
    for (int c = threadIdx.x; c < 3 * 4 * WI; c += 256) {
      const int cig = c & 3, t2 = c >> 2;
      const int col = t2 % WI, r = t2 / WI;
      const int iy = mrow - 1 + r, ix = col - 1;
      u16x8 v = {0, 0, 0, 0, 0, 0, 0, 0};
      if ((unsigned)iy < 32u && (unsigned)ix < 64u)
        v = *(const u16x8*)&ip[(size_t)(iy * 64 + ix) * 64 + cic * 32 + cig * 8];
      *(u16x8*)&X[r][cig][col][0] = v;
    }
    __syncthreads();
#pragma unroll
    for (int u = 0; u < 2; ++u)
#pragma unroll
      for (int vv = 0; vv < 2; ++vv) {
        const int r = (a == 0) ? u : u + 1;
        const int ky = (a == 0) ? 2 * u : 2 * u + 1;
        const int s = (b == 0) ? vv : vv + 1;
        const int kx = (b == 0) ? 2 * vv : 2 * vv + 1;
        bf16x8 bf[4];
#pragma unroll
        for (int j = 0; j < 4; ++j)
          bf[j] = *(const bf16x8*)&X[r][lkg][j * 16 + lm + s][0];
#pragma unroll
        for (int i = 0; i < 2; ++i) {
          bf16x8 af =
              *(const bf16x8*)&wp[((((cic * 4 + ky) * 4 + kx) * 32) + i * 16 + lm) * 32 + lk];
#pragma unroll
          for (int j = 0; j < 4; ++j)
            acc[i * 4 + j] =
                __builtin_amdgcn_mfma_f32_16x16x32_bf16(af, bf[j], acc[i * 4 + j], 0, 0, 0);
        }
      }
  }
#pragma unroll
  for (int i = 0; i < 2; ++i)
#pragma unroll
    for (int j = 0; j < 4; ++j) {
      const int cout0 = i * 16 + lkg * 4;
      const int p = j * 16 + lm;
      const int orow = 2 * mrow + a, ocol = 2 * p + b;
      u16x4 pv;
#pragma unroll
      for (int r2 = 0; r2 < 4; ++r2) pv[r2] = f2b(fmaxf(acc[i * 4 + j][r2], 0.f));
      *(u16x4*)&op[(size_t)(orow * 128 + ocol) * 32 + cout0] = pv;
    }
}

// ---------------------------------------------------------------------------
// conv5 (32->1, 3x3): direct from L2, NHWC input, fp32 out. Thread per pixel.
// ---------------------------------------------------------------------------
__global__ __launch_bounds__(256) void k_conv5m(
    const unsigned short* __restrict__ x5, const float* __restrict__ w5,
    float* __restrict__ out) {
  const int g = blockIdx.y;
  const int pix = blockIdx.x * 256 + threadIdx.x;
  const int y = pix >> 7, x = pix & 127;
  const unsigned short* ip = x5 + (size_t)g * (8192 * 32);
  float s = 0.f;
#pragma unroll
  for (int t = 0; t < 9; ++t) {
    const int yy = y - 1 + t / 3, xx = x - 1 + t % 3;
    if ((unsigned)yy < 64u && (unsigned)xx < 128u) {
#pragma unroll
      for (int cg = 0; cg < 4; ++cg) {
        u16x8 v = *(const u16x8*)&ip[(size_t)(yy * 128 + xx) * 32 + cg * 8];
#pragma unroll
        for (int e = 0; e < 8; ++e) s += b2f(v[e]) * w5[(cg * 8 + e) * 9 + t];
      }
    }
  }
  out[(size_t)g * 8192 + pix] = s;
}

// ---------------------------------------------------------------------------
extern "C" void kernel_launch(void* const* d_in, const int* in_sizes, int n_in,
                              void* d_out, int out_size, void* d_ws, size_t ws_size,
                              hipStream_t stream) {
  const float* f1 = (const float*)d_in[0];
  const float* f2 = (const float*)d_in[1];
  const float* w1 = (const float*)d_in[2];
  const float* w2 = (const float*)d_in[3];
  const float* w3 = (const float*)d_in[4];
  const float* w4 = (const float*)d_in[5];
  const float* wd = (const float*)d_in[6];
  const float* w5 = (const float*)d_in[7];
  float* out = (float*)d_out;

  size_t off = 0;
  auto alloc = [&](size_t bytes) {
    void* p = (char*)d_ws + off;
    off += (bytes + 255) / 256 * 256;
    return p;
  };
  unsigned short* f1b = (unsigned short*)alloc(64 * 128 * 32 * 2);
  unsigned short* f2bp = (unsigned short*)alloc(64 * 128 * 32 * 2);
  unsigned short* w1p = (unsigned short*)alloc(2 * 9 * 96 * 32 * 2);
  unsigned short* w2p = (unsigned short*)alloc(3 * 9 * 128 * 32 * 2);
  unsigned short* w3p = (unsigned short*)alloc(4 * 9 * 128 * 32 * 2);
  unsigned short* w4p = (unsigned short*)alloc(4 * 9 * 64 * 32 * 2);
  unsigned short* wdp = (unsigned short*)alloc(2 * 16 * 32 * 32 * 2);
  unsigned short* z1b = (unsigned short*)alloc((size_t)64 * 128 * 96 * 2);   // bf16
  unsigned short* z2eb = (unsigned short*)alloc((size_t)76 * 140 * 96 * 2);  // bf16
  float* crow = (float*)alloc((size_t)13 * 8 * 128 * 96 * 4);
  float* ccol = (float*)alloc((size_t)13 * 64 * 8 * 96 * 4);
  float* ccor = (float*)alloc((size_t)NITEMS * 8 * 8 * 96 * 4);
  float* rtop = (float*)alloc((size_t)13 * 140 * 96 * 4);
  float* rbot = (float*)alloc((size_t)13 * 140 * 96 * 4);
  float* clft = (float*)alloc((size_t)13 * 76 * 96 * 4);
  float* crgt = (float*)alloc((size_t)13 * 76 * 96 * 4);
  float* kcorn = (float*)alloc((size_t)NITEMS * 4 * 96 * 4);
  const size_t wend = off;

  // Ping-pong slots: P holds x2 then x4; Q holds x3 then x5. 0.5 MiB each.
  const size_t perSlot = (size_t)128 * 2048 * 2;  // bytes
  int G = (int)((ws_size - wend) / (2 * perSlot));
  if (G > NITEMS) G = NITEMS;
  if (G < 1) G = 1;
  unsigned short* P = (unsigned short*)((char*)d_ws + wend);
  unsigned short* Q = (unsigned short*)((char*)d_ws + wend + (size_t)G * perSlot);

  k_prepf<<<32, 256, 0, stream>>>(f1, f1b);
  k_prepf<<<32, 256, 0, stream>>>(f2, f2bp);
  k_prep3x3<<<(96 * 64 * 9 + 255) / 256, 256, 0, stream>>>(w1, w1p, 96, 64);
  k_prep3x3<<<(128 * 96 * 9 + 255) / 256, 256, 0, stream>>>(w2, w2p, 128, 96);
  k_prep3x3<<<(128 * 128 * 9 + 255) / 256, 256, 0, stream>>>(w3, w3p, 128, 128);
  k_prep3x3<<<(64 * 128 * 9 + 255) / 256, 256, 0, stream>>>(w4, w4p, 64, 128);
  k_prepwd<<<(32 * 64 * 16 + 255) / 256, 256, 0, stream>>>(wd, wdp);

  k_z1<<<32, 256, 0, stream>>>(f1b, w1p, z1b);
  k_z2e<<<76, 256, 0, stream>>>(f2bp, w1p, z2eb);
  k_crow<<<91, 256, 0, stream>>>(f1b, w1p, crow);
  k_ccol<<<13, 256, 0, stream>>>(f1b, w1p, ccol);
  k_ccorner<<<(NITEMS * 64 * 96 + 255) / 256, 256, 0, stream>>>(f1b, w1p, ccor);
  k_bcorr_rows<<<(13 * 140 * 96 + 255) / 256, 256, 0, stream>>>(f2bp, w1p, rtop, rbot);
  k_bcorr_cols<<<(13 * 76 * 96 + 255) / 256, 256, 0, stream>>>(f2bp, w1p, clft, crgt);
  k_bcorr_corn<<<(NITEMS * 4 * 96 + 255) / 256, 256, 0, stream>>>(f2bp, w1p, kcorn);

  for (int base = 0; base < NITEMS; base += G) {
    const int cnt = (NITEMS - base < G) ? (NITEMS - base) : G;
    // x2 = relu(conv2(x1_onthefly))      : P
    k_conv2f<<<dim3(32, cnt), 256, 0, stream>>>(z1b, z2eb, crow, ccol, ccor, rtop, rbot,
                                                clft, crgt, kcorn, w2p, P, base);
    // x3 = relu(conv3(x2))               : Q
    k_convm<128, 128, 32, 64, 1, true><<<dim3(32, cnt), 256, 0, stream>>>(P, w3p, Q);
    // x4 = relu(conv4(x3))               : P (x2 dead)
    k_convm<128, 64, 32, 64, 1, true><<<dim3(32, cnt), 256, 0, stream>>>(Q, w4p, P);
    // x5 = relu(deconv(x4))              : Q (x3 dead)
    k_deconvm<<<dim3(32, cnt), 256, 0, stream>>>(P, wdp, Q);
    // cost = conv5(x5)                   : out
    k_conv5m<<<dim3(32, cnt), 256, 0, stream>>>(Q, w5, out + (size_t)base * 8192);
  }
}